// Round 6
// baseline (6848.784 us; speedup 1.0000x reference)
//
#include <hip/hip_runtime.h>

typedef __attribute__((ext_vector_type(8))) _Float16 f16x8;
typedef __attribute__((ext_vector_type(4))) _Float16 f16x4;
typedef __attribute__((ext_vector_type(4))) float    f32x4;

#define HD    256
#define TIN   48
#define TOUT  24
#define MBG   128            // batch rows per 4-CU group
#define HSTR  264            // hF stride (halves): h only (k 0..255), 2-way-free banks
#define GSTR  132            // gates buffer column stride (halves)
#define ENC_FRAGS 576        // 4 roles x 8 waves x 2 ct x 9 kt
#define DEC_FRAGS 512        // 4 roles x 8 waves x 2 ct x 8 kt
#define PREP_HALVES ((ENC_FRAGS + DEC_FRAGS) * 512)     // 557056
#define SL_OFF   PREP_HALVES                            // slices start (halves)
#define SLICE_HALVES 8192                               // 128 rows x 64 units
#define FLAG_BYTE_OFF ((SL_OFF + 64 * 4 * SLICE_HALVES) * 2)  // 5308416
#define FLAG_BYTES (64 * 128 * 4)

template <int N> struct KTag { static constexpr int val = N; };

// Fragment-major fp16 weights grouped by (role, wave, ct, kt).
// role r owns ntiles {r, r+4, r+8, r+12}; wave w owns ct pair {2w, 2w+1} where
// ct = g*4 + i -> gate g, ntile 4*i + r.  Frag content (b-operand):
//   b[lane][s] = W[k = kt*32 + (lane>>4)*8 + s][col = nt*16 + (lane&15)]
__global__ void prep_frags(const float* __restrict__ enc_Wih,
                           const float* __restrict__ enc_Whh,
                           const float* __restrict__ dec_Whh,
                           _Float16* __restrict__ wf)
{
    int p = blockIdx.x * blockDim.x + threadIdx.x;
    if (p >= PREP_HALVES) return;
    int lane = (p >> 3) & 63;
    int s    = p & 7;
    int kq   = ((lane >> 4) << 3) + s;
    int l15  = lane & 15;
    float v  = 0.0f;
    if (p < ENC_FRAGS * 512) {
        int fi = p >> 9;
        int kt = fi % 9; int q1 = fi / 9;
        int j = q1 & 1; int q2 = q1 >> 1;
        int wv = q2 & 7, role = q2 >> 3;
        int ct = 2 * wv + j, g = ct >> 2, i = ct & 3, nt = 4 * i + role;
        int col = nt * 16 + l15;
        int row = g * 256 + col;
        int k = kt * 32 + kq;
        if (k < 256)      v = enc_Whh[row * 256 + k];
        else if (k < 272) v = enc_Wih[row * 16 + (k - 256)];
    } else {
        int p2 = p - ENC_FRAGS * 512;
        int fi = p2 >> 9;
        int kt = fi & 7; int q1 = fi >> 3;
        int j = q1 & 1; int q2 = q1 >> 1;
        int wv = q2 & 7, role = q2 >> 3;
        int ct = 2 * wv + j, g = ct >> 2, i = ct & 3, nt = 4 * i + role;
        int col = nt * 16 + l15;
        int row = g * 256 + col;
        int k = kt * 32 + kq;
        v = dec_Whh[row * 256 + k];
    }
    wf[p] = (_Float16)v;
}

__device__ __forceinline__ float sigm(float v) {
    return __builtin_amdgcn_rcpf(1.0f + __expf(-v));
}
__device__ __forceinline__ float tanh_f(float v) {
    return 1.0f - 2.0f * __builtin_amdgcn_rcpf(1.0f + __expf(2.0f * v));
}

// 256 blocks x 512 threads, 1 block/CU (LDS ~148 KB forces it; grid == #CUs so
// all blocks co-resident). Block = (gid = blockIdx&63, role = blockIdx>>6).
// Group {gid, gid+64, gid+128, gid+192} shares batch rows [gid*128, +128) and
// splits the 1024 gate-cols 4 ways; under round-robin blockIdx->XCD all four
// members sit on XCD gid%8 (perf heuristic; correctness via device-scope
// atomics + __threadfence regardless of placement).
__global__ __launch_bounds__(512, 2) void seq2seq_pers(
    const float* __restrict__ x,
    _Float16* __restrict__ wsh,
    const float* __restrict__ enc_b,
    const float* __restrict__ dec_b,
    const float* __restrict__ denseW,
    const float* __restrict__ denseb,
    float* __restrict__ out,
    int* __restrict__ flags)
{
    __shared__ __align__(16) _Float16 hF[MBG * HSTR];        // 66 KB: h only
    __shared__ __align__(16) _Float16 gT[256 * GSTR + 256];  // 66.5 KB gates
    __shared__ __align__(16) _Float16 xsb[4 * MBG * 16];     // 16 KB x chunk

    const int tid  = threadIdx.x;
    const int wv   = tid >> 6;        // wave = ct-pair owner (gemm) / rgroup (pointwise)
    const int lane = tid & 63;
    const int quad = lane >> 4;
    const int l15  = lane & 15;
    const int gid  = blockIdx.x & 63;
    const int role = blockIdx.x >> 6;
    const int n0   = gid * MBG;

    const _Float16* wf = wsh;
    _Float16* slices = wsh + SL_OFF;

    // ---- persistent register weights ----
    f16x8 wE[18], wD[16];
    #pragma unroll
    for (int j = 0; j < 2; ++j)
        #pragma unroll
        for (int kt = 0; kt < 9; ++kt)
            wE[j * 9 + kt] = *(const f16x8*)(wf + ((size_t)((((role * 8 + wv) * 2 + j) * 9) + kt) << 9) + lane * 8);
    #pragma unroll
    for (int j = 0; j < 2; ++j)
        #pragma unroll
        for (int kt = 0; kt < 8; ++kt)
            wD[j * 8 + kt] = *(const f16x8*)(wf + ((size_t)(ENC_FRAGS + (((role * 8 + wv) * 2 + j) * 8) + kt) << 9) + lane * 8);

    float bE[2], bD[2];
    #pragma unroll
    for (int j = 0; j < 2; ++j) {
        int ct = 2 * wv + j, g = ct >> 2, i = ct & 3, nt = 4 * i + role;
        int col = nt * 16 + l15;
        bE[j] = enc_b[g * 256 + col];
        bD[j] = dec_b[g * 256 + col];
    }

    for (int idx = tid; idx < MBG * HSTR; idx += 512) hF[idx] = (_Float16)0;

    auto loadchunk = [&](int ch) {   // x[:, :, ch*4 .. ch*4+4) -> xsb[tt][m][c]
        #pragma unroll
        for (int kk = 0; kk < 4; ++kk) {
            int mc = tid + kk * 512, m = mc >> 4, c = mc & 15;
            float4 v = *(const float4*)(x + (size_t)(n0 + m) * 768 + c * 48 + ch * 4);
            xsb[(0 * MBG + m) * 16 + c] = (_Float16)v.x;
            xsb[(1 * MBG + m) * 16 + c] = (_Float16)v.y;
            xsb[(2 * MBG + m) * 16 + c] = (_Float16)v.z;
            xsb[(3 * MBG + m) * 16 + c] = (_Float16)v.w;
        }
    };
    loadchunk(0);
    __syncthreads();

    f32x4 acc[2][8];
    float cst[16];
    _Float16 hval[16];
    #pragma unroll
    for (int r = 0; r < 16; ++r) cst[r] = 0.0f;
    const f16x8 zero8 = {};

    auto gemm = [&](auto ktc, auto& W, float b0, float b1, int t) {
        constexpr int KT = decltype(ktc)::val;
        #pragma unroll
        for (int j = 0; j < 2; ++j) {
            float b = j ? b1 : b0;
            #pragma unroll
            for (int mt = 0; mt < 8; ++mt) acc[j][mt] = (f32x4){b, b, b, b};
        }
        #pragma unroll
        for (int kt = 0; kt < KT; ++kt) {
            #pragma unroll
            for (int mt = 0; mt < 8; ++mt) {
                f16x8 a;
                if (KT == 9 && kt == 8) {
                    a = (quad < 2)
                        ? *(const f16x8*)(xsb + ((t & 3) * MBG + mt * 16 + l15) * 16 + quad * 8)
                        : zero8;
                } else {
                    a = *(const f16x8*)(hF + (mt * 16 + l15) * HSTR + kt * 32 + quad * 8);
                }
                acc[0][mt] = __builtin_amdgcn_mfma_f32_16x16x32_f16(a, W[0 * KT + kt], acc[0][mt], 0, 0, 0);
                acc[1][mt] = __builtin_amdgcn_mfma_f32_16x16x32_f16(a, W[1 * KT + kt], acc[1][mt], 0, 0, 0);
            }
        }
    };

    auto gwrite = [&]() {   // acc -> gates buffer, column-major [ct*16+l15][row]
        #pragma unroll
        for (int j = 0; j < 2; ++j) {
            int ct = 2 * wv + j;
            int base = (ct * 16 + l15) * GSTR + ct * 8 + quad * 4;
            #pragma unroll
            for (int mt = 0; mt < 8; ++mt) {
                f16x4 v = { (_Float16)acc[j][mt][0], (_Float16)acc[j][mt][1],
                            (_Float16)acc[j][mt][2], (_Float16)acc[j][mt][3] };
                *(f16x4*)(gT + base + mt * 16) = v;
            }
        }
    };

    // pointwise: thread = (rgroup = wv: rows wv*16..+16) x (unit u = lane)
    auto pointw = [&]() {
        f16x4 gc[4][4];
        #pragma unroll
        for (int g = 0; g < 4; ++g) {
            int ct = g * 4 + quad;
            int cb = (ct * 16 + l15) * GSTR + ct * 8 + wv * 16;
            #pragma unroll
            for (int ch = 0; ch < 4; ++ch)
                gc[g][ch] = *(const f16x4*)(gT + cb + ch * 4);
        }
        #pragma unroll
        for (int rr = 0; rr < 16; ++rr) {
            float iv = sigm((float)gc[0][rr >> 2][rr & 3]);
            float fv = sigm((float)gc[1][rr >> 2][rr & 3]);
            float gg = tanh_f((float)gc[2][rr >> 2][rr & 3]);
            float ov = sigm((float)gc[3][rr >> 2][rr & 3]);
            float cn = fmaf(fv, cst[rr], iv * gg);
            cst[rr] = cn;
            hval[rr] = (_Float16)(ov * tanh_f(cn));
        }
        _Float16* smy = slices + (gid * 4 + role) * SLICE_HALVES;
        #pragma unroll
        for (int rr = 0; rr < 16; ++rr)
            smy[(wv * 16 + rr) * 64 + lane] = hval[rr];
    };

    auto exchange = [&](int s) {
        __threadfence();              // release own slice stores (device scope)
        __syncthreads();              // whole block's stores fenced
        int* fl = flags + gid * 128 + s;
        if (tid == 0) {
            atomicAdd(fl, 1);
            while (atomicAdd(fl, 0) < 4) __builtin_amdgcn_s_sleep(2);
        }
        __syncthreads();
        __threadfence();              // acquire: invalidate caches before reads
        #pragma unroll
        for (int rp = 0; rp < 4; ++rp) {
            const _Float16* sr = slices + (gid * 4 + rp) * SLICE_HALVES;
            #pragma unroll
            for (int q = 0; q < 2; ++q) {
                int idx = tid + q * 512;
                int m = idx >> 3, u0 = (idx & 7) * 8;
                f16x8 v = *(const f16x8*)(sr + m * 64 + u0);
                int i = u0 >> 4, lu0 = u0 & 15;
                *(f16x8*)(hF + m * HSTR + (4 * i + rp) * 16 + lu0) = v;
            }
        }
    };

    // ================= encoder =================
    for (int t = 0; t < TIN; ++t) {
        gemm(KTag<9>{}, wE, bE[0], bE[1], t);
        gwrite();
        __syncthreads();             // gates complete; hF reads complete
        pointw();
        exchange(t);                 // fence/flag/poll + rebuild hF = h_{t+1}
        if (((t + 1) & 3) == 0 && t + 1 < TIN) loadchunk((t + 1) >> 2);
        __syncthreads();             // hF + x chunk ready for next gemm
    }

    // ================= decoder (c resets to 0) =================
    #pragma unroll
    for (int r = 0; r < 16; ++r) cst[r] = 0.0f;

    for (int t = 0; t < TOUT; ++t) {
        gemm(KTag<8>{}, wD, bD[0], bD[1], 0);
        gwrite();
        __syncthreads();
        pointw();
        exchange(48 + t);
        __syncthreads();             // hF = hs[t] ready
        // dense: member computes its 32-row share; hF stays valid until the
        // next step's rebuild, which is ordered behind two barriers.
        if (tid < 256) {
            int m = role * 32 + (tid >> 3), o = tid & 7;
            const float* wr = denseW + (t * 8 + o) * HD;
            float s = denseb[t * 8 + o];
            #pragma unroll 4
            for (int j8 = 0; j8 < 32; ++j8) {
                f16x8 hv  = *(const f16x8*)(hF + m * HSTR + j8 * 8);
                float4 w0 = *(const float4*)(wr + j8 * 8);
                float4 w1 = *(const float4*)(wr + j8 * 8 + 4);
                s = fmaf((float)hv[0], w0.x, s);
                s = fmaf((float)hv[1], w0.y, s);
                s = fmaf((float)hv[2], w0.z, s);
                s = fmaf((float)hv[3], w0.w, s);
                s = fmaf((float)hv[4], w1.x, s);
                s = fmaf((float)hv[5], w1.y, s);
                s = fmaf((float)hv[6], w1.z, s);
                s = fmaf((float)hv[7], w1.w, s);
            }
            out[(size_t)(n0 + m) * 192 + o * 24 + t] = s;
        }
    }
}

extern "C" void kernel_launch(void* const* d_in, const int* in_sizes, int n_in,
                              void* d_out, int out_size, void* d_ws, size_t ws_size,
                              hipStream_t stream) {
    const float* x       = (const float*)d_in[0];
    const float* enc_Wih = (const float*)d_in[1];
    const float* enc_Whh = (const float*)d_in[2];
    const float* enc_b   = (const float*)d_in[3];
    const float* dec_Whh = (const float*)d_in[4];
    const float* dec_b   = (const float*)d_in[5];
    const float* denseW  = (const float*)d_in[6];
    const float* denseb  = (const float*)d_in[7];
    float* out = (float*)d_out;
    _Float16* wsh = (_Float16*)d_ws;            // frags | slices | flags (~5.4 MB)
    int* flags = (int*)((char*)d_ws + FLAG_BYTE_OFF);

    hipMemsetAsync(flags, 0, FLAG_BYTES, stream);
    prep_frags<<<(PREP_HALVES + 255) / 256, 256, 0, stream>>>(enc_Wih, enc_Whh, dec_Whh, wsh);
    seq2seq_pers<<<256, 512, 0, stream>>>(x, wsh, enc_b, dec_b, denseW, denseb, out, flags);
}

// Round 7
// 1467.041 us; speedup vs baseline: 4.6684x; 4.6684x over previous
//
#include <hip/hip_runtime.h>

typedef __attribute__((ext_vector_type(8))) _Float16 f16x8;
typedef __attribute__((ext_vector_type(4))) float    f32x4;

#define HD    256
#define CIN   16
#define TIN   48
#define TOUT  24
#define COUT  8
#define MB    32            // batch rows per block
#define KPAD  296           // padded row stride (halves) for hF
#define KT_ENC 9            // K = 288 (h 256 | x 16 | pad 16)
#define KT_DEC 8            // K = 256
#define WE_HALVES (KT_ENC*4*16*512)   // 294912
#define WD_HALVES (KT_DEC*4*16*512)   // 262144
#define PREP_TOTAL (WE_HALVES + WD_HALVES)

template <int N> struct KTag { static constexpr int val = N; };

// Fragment-major fp16 weights: frag id = kt*64 + g*16 + ntile, each frag is
// 64 lanes x 8 halves with b_frag[lane][s] = W[k = kt*32 + (lane>>4)*8 + s]
//                                             [col = g*256 + ntile*16 + (lane&15)]
__global__ void prep_frags(const float* __restrict__ enc_Wih,
                           const float* __restrict__ enc_Whh,
                           const float* __restrict__ dec_Whh,
                           _Float16* __restrict__ wf)
{
    int p = blockIdx.x * blockDim.x + threadIdx.x;
    if (p >= PREP_TOTAL) return;
    int lane = (p >> 3) & 63;
    int s    = p & 7;
    int kq   = ((lane >> 4) << 3) + s;
    int l15  = lane & 15;
    float v;
    if (p < WE_HALVES) {
        int frag = p >> 9;
        int kt = frag >> 6, g = (frag >> 4) & 3, ntile = frag & 15;
        int k   = kt * 32 + kq;
        int row = g * 256 + ntile * 16 + l15;
        v = 0.0f;
        if (k < 256)      v = enc_Whh[row * 256 + k];
        else if (k < 272) v = enc_Wih[row * 16 + (k - 256)];
    } else {
        int q = p - WE_HALVES;
        int frag = q >> 9;
        int kt = frag >> 6, g = (frag >> 4) & 3, ntile = frag & 15;
        int k   = kt * 32 + kq;
        int row = g * 256 + ntile * 16 + l15;
        v = dec_Whh[row * 256 + k];
    }
    wf[p] = (_Float16)v;
}

__device__ __forceinline__ float sigm(float v) {
    return __builtin_amdgcn_rcpf(1.0f + __expf(-v));
}
__device__ __forceinline__ float tanh_f(float v) {
    return 1.0f - 2.0f * __builtin_amdgcn_rcpf(1.0f + __expf(2.0f * v));
}

// grid = 256 blocks (1/CU), 512 threads = 8 waves (2/SIMD -> 256 VGPR/wave).
// Wave w owns ntiles {2w, 2w+1} for all 4 gates, both 16-row M-tiles.
// 24 weight frags/wave (g<2, kt<6) pinned in VGPRs (96 regs); rest streamed.
// Same registers are reloaded with decoder frags at the phase switch.
__global__ __launch_bounds__(512, 2) void seq2seq_mfma(
    const float* __restrict__ x,
    const _Float16* __restrict__ wf,
    const float* __restrict__ enc_b,
    const float* __restrict__ dec_b,
    const float* __restrict__ denseW,
    const float* __restrict__ denseb,
    float* __restrict__ out)
{
    __shared__ __align__(16) _Float16 hF[MB * KPAD];          // 18.5 KB
    __shared__ __align__(16) _Float16 xs[2][MB * CIN * 8];    // 16 KB
    __shared__ __align__(16) float    outS[MB * COUT * TOUT]; // 24 KB

    const int tid  = threadIdx.x;
    const int w    = tid >> 6;
    const int lane = tid & 63;
    const int quad = lane >> 4;
    const int l15  = lane & 15;
    const int n0   = blockIdx.x * MB;

    float bE[4][2], bD[4][2];
    #pragma unroll
    for (int g = 0; g < 4; ++g)
        #pragma unroll
        for (int nt = 0; nt < 2; ++nt) {
            int col = (w * 2 + nt) * 16 + l15;
            bE[g][nt] = enc_b[g * 256 + col];
            bD[g][nt] = dec_b[g * 256 + col];
        }

    auto loadchunk = [&](int wd) {   // stage x[:, :, wd*8 .. wd*8+8) -> xs[wd&1]
        int m = tid >> 4, c = tid & 15;
        const float* xp = x + (size_t)(n0 + m) * (CIN * TIN) + c * TIN + wd * 8;
        float4 v0 = *(const float4*)xp;
        float4 v1 = *(const float4*)(xp + 4);
        f16x8 hv = { (_Float16)v0.x, (_Float16)v0.y, (_Float16)v0.z, (_Float16)v0.w,
                     (_Float16)v1.x, (_Float16)v1.y, (_Float16)v1.z, (_Float16)v1.w };
        *(f16x8*)(&xs[wd & 1][m * (CIN * 8) + c * 8]) = hv;
    };
    auto xcopy = [&](int t) {        // xs -> hF x-slot for step t
        int m = tid >> 4, c = tid & 15;
        hF[m * KPAD + 256 + c] = xs[(t >> 3) & 1][m * (CIN * 8) + c * 8 + (t & 7)];
    };

    for (int i = tid; i < MB * KPAD; i += 512) hF[i] = (_Float16)0.0f;
    loadchunk(0);
    __syncthreads();
    xcopy(0);
    __syncthreads();

    // ---- register-pinned weight fragments: [nt][kt<6][g<2] -> nt*12+kt*2+g ----
    f16x8 wreg[24];
    auto loadheld = [&](const _Float16* base) {
        #pragma unroll
        for (int nt = 0; nt < 2; ++nt)
            #pragma unroll
            for (int kt = 0; kt < 6; ++kt)
                #pragma unroll
                for (int g = 0; g < 2; ++g)
                    wreg[nt * 12 + kt * 2 + g] =
                        *(const f16x8*)(base + ((size_t)(kt * 64 + g * 16 + w * 2 + nt) << 9) + lane * 8);
    };
    loadheld(wf);   // encoder frags

    f32x4 acc[2][4][2];        // [Mtile][gate][nt]
    float cst[2][2][4];        // c-state, C-frag layout
    #pragma unroll
    for (int mt = 0; mt < 2; ++mt)
        #pragma unroll
        for (int nt = 0; nt < 2; ++nt)
            #pragma unroll
            for (int r = 0; r < 4; ++r) cst[mt][nt][r] = 0.0f;

    const f16x8* Ap0 = (const f16x8*)(hF + l15 * KPAD);          // Mtile 0
    const f16x8* Ap1 = (const f16x8*)(hF + (16 + l15) * KPAD);   // Mtile 1
    const f16x8* WpE = (const f16x8*)wf + (w * 2) * 64 + lane;
    const f16x8* WpD = (const f16x8*)(wf + WE_HALVES) + (w * 2) * 64 + lane;

    auto gemm = [&](auto kt_tag, const f16x8* __restrict__ Wp, const float (&bias)[4][2]) {
        constexpr int KT = decltype(kt_tag)::val;
        #pragma unroll
        for (int mt = 0; mt < 2; ++mt)
            #pragma unroll
            for (int g = 0; g < 4; ++g)
                #pragma unroll
                for (int nt = 0; nt < 2; ++nt) {
                    float b = bias[g][nt];
                    f32x4 bv = {b, b, b, b};
                    acc[mt][g][nt] = bv;
                }
        #pragma unroll
        for (int kt = 0; kt < KT; ++kt) {
            f16x8 a0 = Ap0[kt * 4 + quad];
            f16x8 a1 = Ap1[kt * 4 + quad];
            #pragma unroll
            for (int g = 0; g < 4; ++g)
                #pragma unroll
                for (int nt = 0; nt < 2; ++nt) {
                    f16x8 bf;
                    if (g < 2 && kt < 6)
                        bf = wreg[nt * 12 + kt * 2 + g];        // register-pinned
                    else
                        bf = Wp[(kt * 64 + g * 16 + nt) * 64];  // streamed from L2/L3
                    acc[0][g][nt] = __builtin_amdgcn_mfma_f32_16x16x32_f16(a0, bf, acc[0][g][nt], 0, 0, 0);
                    acc[1][g][nt] = __builtin_amdgcn_mfma_f32_16x16x32_f16(a1, bf, acc[1][g][nt], 0, 0, 0);
                }
        }
    };

    auto pointwise = [&]() {
        #pragma unroll
        for (int mt = 0; mt < 2; ++mt)
            #pragma unroll
            for (int nt = 0; nt < 2; ++nt) {
                int col = (w * 2 + nt) * 16 + l15;
                #pragma unroll
                for (int r = 0; r < 4; ++r) {
                    float iv = sigm(acc[mt][0][nt][r]);
                    float fv = sigm(acc[mt][1][nt][r]);
                    float gv = tanh_f(acc[mt][2][nt][r]);
                    float ov = sigm(acc[mt][3][nt][r]);
                    float cn = fmaf(fv, cst[mt][nt][r], iv * gv);
                    cst[mt][nt][r] = cn;
                    float hv = ov * tanh_f(cn);
                    hF[(mt * 16 + quad * 4 + r) * KPAD + col] = (_Float16)hv;
                }
            }
    };

    // ================= encoder =================
    for (int t = 0; t < TIN; ++t) {
        gemm(KTag<KT_ENC>{}, WpE, bE);
        __syncthreads();              // all A-frag reads done
        pointwise();                  // write h_t
        if ((t & 7) == 0 && (t >> 3) + 1 < 6) loadchunk((t >> 3) + 1);
        if (t + 1 < TIN) xcopy(t + 1);
        __syncthreads();
    }

    // ================= decoder (c resets to 0) =================
    loadheld(wf + WE_HALVES);   // swap pinned registers to decoder frags
    #pragma unroll
    for (int mt = 0; mt < 2; ++mt)
        #pragma unroll
        for (int nt = 0; nt < 2; ++nt)
            #pragma unroll
            for (int r = 0; r < 4; ++r) cst[mt][nt][r] = 0.0f;

    for (int t = 0; t < TOUT; ++t) {
        gemm(KTag<KT_DEC>{}, WpD, bD);
        __syncthreads();
        pointwise();
        __syncthreads();
        // dense epilogue -> LDS out buffer (threads 0..255). hF is read-only
        // until the next step's post-gemm barrier -> race-free.
        if (tid < MB * COUT) {
            int m = tid >> 3, o = tid & 7;
            const float* wr = denseW + (t * COUT + o) * HD;
            float s = denseb[t * COUT + o];
            #pragma unroll 4
            for (int j8 = 0; j8 < 32; ++j8) {
                f16x8 hv  = *(const f16x8*)(hF + m * KPAD + j8 * 8);
                float4 w0 = *(const float4*)(wr + j8 * 8);
                float4 w1 = *(const float4*)(wr + j8 * 8 + 4);
                s = fmaf((float)hv[0], w0.x, s);
                s = fmaf((float)hv[1], w0.y, s);
                s = fmaf((float)hv[2], w0.z, s);
                s = fmaf((float)hv[3], w0.w, s);
                s = fmaf((float)hv[4], w1.x, s);
                s = fmaf((float)hv[5], w1.y, s);
                s = fmaf((float)hv[6], w1.z, s);
                s = fmaf((float)hv[7], w1.w, s);
            }
            outS[m * (COUT * TOUT) + o * TOUT + t] = s;
        }
    }

    // ================= coalesced output flush =================
    __syncthreads();
    {
        const float4* src = (const float4*)outS;
        float4* dst = (float4*)(out + (size_t)n0 * (COUT * TOUT));
        #pragma unroll
        for (int i = 0; i < (MB * COUT * TOUT / 4) / 512; ++i)
            dst[tid + i * 512] = src[tid + i * 512];
    }
}

extern "C" void kernel_launch(void* const* d_in, const int* in_sizes, int n_in,
                              void* d_out, int out_size, void* d_ws, size_t ws_size,
                              hipStream_t stream) {
    const float* x       = (const float*)d_in[0];
    const float* enc_Wih = (const float*)d_in[1];
    const float* enc_Whh = (const float*)d_in[2];
    const float* enc_b   = (const float*)d_in[3];
    const float* dec_Whh = (const float*)d_in[4];
    const float* dec_b   = (const float*)d_in[5];
    const float* denseW  = (const float*)d_in[6];
    const float* denseb  = (const float*)d_in[7];
    float* out = (float*)d_out;
    _Float16* wf = (_Float16*)d_ws;   // 1.09 MB fragment-major fp16 weights

    prep_frags<<<(PREP_TOTAL + 255) / 256, 256, 0, stream>>>(enc_Wih, enc_Whh, dec_Whh, wf);
    seq2seq_mfma<<<8192 / MB, 512, 0, stream>>>(x, wf, enc_b, dec_b, denseW, denseb, out);
}

// Round 8
// 1406.372 us; speedup vs baseline: 4.8698x; 1.0431x over previous
//
#include <hip/hip_runtime.h>

typedef __attribute__((ext_vector_type(8))) _Float16 f16x8;
typedef __attribute__((ext_vector_type(4))) float    f32x4;

#define HD    256
#define CIN   16
#define TIN   48
#define TOUT  24
#define COUT  8
#define MB    32            // batch rows per block
#define KPAD  296           // padded row stride (halves) for hF
#define KT_ENC 9            // K = 288 (h 256 | x 16 | pad 16)
#define KT_DEC 8            // K = 256
#define WE_HALVES (KT_ENC*4*16*512)   // 294912
#define WD_HALVES (KT_DEC*4*16*512)   // 262144
#define PREP_TOTAL (WE_HALVES + WD_HALVES)
#define NREP  8             // one weight-buffer copy per XCD

template <int N> struct KTag { static constexpr int val = N; };

// Fragment-major fp16 weights: frag id = kt*64 + g*16 + ntile, each frag is
// 64 lanes x 8 halves with b_frag[lane][s] = W[k = kt*32 + (lane>>4)*8 + s]
//                                             [col = g*256 + ntile*16 + (lane&15)]
// Written NREP times (copy r at offset r*PREP_TOTAL) so each XCD reads its
// own address range -> no cross-XCD same-line contention beyond L2.
__global__ void prep_frags(const float* __restrict__ enc_Wih,
                           const float* __restrict__ enc_Whh,
                           const float* __restrict__ dec_Whh,
                           _Float16* __restrict__ wf)
{
    int p = blockIdx.x * blockDim.x + threadIdx.x;
    if (p >= PREP_TOTAL) return;
    int lane = (p >> 3) & 63;
    int s    = p & 7;
    int kq   = ((lane >> 4) << 3) + s;
    int l15  = lane & 15;
    float v;
    if (p < WE_HALVES) {
        int frag = p >> 9;
        int kt = frag >> 6, g = (frag >> 4) & 3, ntile = frag & 15;
        int k   = kt * 32 + kq;
        int row = g * 256 + ntile * 16 + l15;
        v = 0.0f;
        if (k < 256)      v = enc_Whh[row * 256 + k];
        else if (k < 272) v = enc_Wih[row * 16 + (k - 256)];
    } else {
        int q = p - WE_HALVES;
        int frag = q >> 9;
        int kt = frag >> 6, g = (frag >> 4) & 3, ntile = frag & 15;
        int k   = kt * 32 + kq;
        int row = g * 256 + ntile * 16 + l15;
        v = dec_Whh[row * 256 + k];
    }
    _Float16 hv = (_Float16)v;
    #pragma unroll
    for (int rep = 0; rep < NREP; ++rep)
        wf[(size_t)rep * PREP_TOTAL + p] = hv;
}

__device__ __forceinline__ float sigm(float v) {
    return __builtin_amdgcn_rcpf(1.0f + __expf(-v));
}
__device__ __forceinline__ float tanh_f(float v) {
    return 1.0f - 2.0f * __builtin_amdgcn_rcpf(1.0f + __expf(2.0f * v));
}

// grid = 256 blocks (1/CU), 1024 threads = 16 waves (4/SIMD). Wave w owns
// ntile w: unit-columns [w*16, w*16+16) for all 4 gates, both 16-row M-tiles.
__global__ __launch_bounds__(1024, 4) void seq2seq_mfma(
    const float* __restrict__ x,
    const _Float16* __restrict__ wf,
    const float* __restrict__ enc_b,
    const float* __restrict__ dec_b,
    const float* __restrict__ denseW,
    const float* __restrict__ denseb,
    float* __restrict__ out)
{
    __shared__ __align__(16) _Float16 hF[MB * KPAD];          // 18.5 KB
    __shared__ __align__(16) _Float16 xs[2][MB * CIN * 8];    // 16 KB
    __shared__ __align__(16) float    outS[MB * COUT * TOUT]; // 24 KB

    const int tid  = threadIdx.x;
    const int w    = tid >> 6;       // 0..15 = ntile
    const int lane = tid & 63;
    const int quad = lane >> 4;
    const int l15  = lane & 15;
    const int n0   = blockIdx.x * MB;

    // per-XCD weight copy (round-robin blockIdx->XCD heuristic; any mapping
    // still spreads beyond-L2 traffic over 8 address ranges)
    const _Float16* wfb = wf + (size_t)(blockIdx.x & 7) * PREP_TOTAL;

    float bE[4], bD[4];
    #pragma unroll
    for (int g = 0; g < 4; ++g) {
        int col = w * 16 + l15;
        bE[g] = enc_b[g * 256 + col];
        bD[g] = dec_b[g * 256 + col];
    }

    auto loadchunk = [&](int wd) {   // stage x[:, :, wd*8 .. wd*8+8) -> xs[wd&1]
        if (tid < 512) {
            int m = tid >> 4, c = tid & 15;
            const float* xp = x + (size_t)(n0 + m) * (CIN * TIN) + c * TIN + wd * 8;
            float4 v0 = *(const float4*)xp;
            float4 v1 = *(const float4*)(xp + 4);
            f16x8 hv = { (_Float16)v0.x, (_Float16)v0.y, (_Float16)v0.z, (_Float16)v0.w,
                         (_Float16)v1.x, (_Float16)v1.y, (_Float16)v1.z, (_Float16)v1.w };
            *(f16x8*)(&xs[wd & 1][m * (CIN * 8) + c * 8]) = hv;
        }
    };
    auto xcopy = [&](int t) {        // xs -> hF x-slot for step t
        if (tid < 512) {
            int m = tid >> 4, c = tid & 15;
            hF[m * KPAD + 256 + c] = xs[(t >> 3) & 1][m * (CIN * 8) + c * 8 + (t & 7)];
        }
    };

    for (int i = tid; i < MB * KPAD; i += 1024) hF[i] = (_Float16)0.0f;
    loadchunk(0);
    __syncthreads();
    xcopy(0);
    __syncthreads();

    f32x4 acc[2][4];        // [Mtile][gate]
    float cst[2][4];        // c-state, C-frag layout rows
    #pragma unroll
    for (int mt = 0; mt < 2; ++mt)
        #pragma unroll
        for (int r = 0; r < 4; ++r) cst[mt][r] = 0.0f;

    const f16x8* Ap0 = (const f16x8*)(hF + l15 * KPAD);          // Mtile 0
    const f16x8* Ap1 = (const f16x8*)(hF + (16 + l15) * KPAD);   // Mtile 1
    const f16x8* WpE = (const f16x8*)wfb + w * 64 + lane;
    const f16x8* WpD = (const f16x8*)(wfb + WE_HALVES) + w * 64 + lane;

    auto gemm = [&](auto kt_tag, const f16x8* __restrict__ Wp, const float (&bias)[4]) {
        constexpr int KT = decltype(kt_tag)::val;
        #pragma unroll
        for (int mt = 0; mt < 2; ++mt)
            #pragma unroll
            for (int g = 0; g < 4; ++g) {
                float b = bias[g];
                f32x4 bv = {b, b, b, b};
                acc[mt][g] = bv;
            }
        #pragma unroll
        for (int kt = 0; kt < KT; ++kt) {
            f16x8 a0 = Ap0[kt * 4 + quad];
            f16x8 a1 = Ap1[kt * 4 + quad];
            #pragma unroll
            for (int g = 0; g < 4; ++g) {
                f16x8 bf = Wp[(kt * 4 + g) * 1024];   // frag (kt*64 + g*16 + w)
                acc[0][g] = __builtin_amdgcn_mfma_f32_16x16x32_f16(a0, bf, acc[0][g], 0, 0, 0);
                acc[1][g] = __builtin_amdgcn_mfma_f32_16x16x32_f16(a1, bf, acc[1][g], 0, 0, 0);
            }
        }
    };

    auto pointwise = [&]() {
        int col = w * 16 + l15;
        #pragma unroll
        for (int mt = 0; mt < 2; ++mt)
            #pragma unroll
            for (int r = 0; r < 4; ++r) {
                float iv = sigm(acc[mt][0][r]);
                float fv = sigm(acc[mt][1][r]);
                float gv = tanh_f(acc[mt][2][r]);
                float ov = sigm(acc[mt][3][r]);
                float cn = fmaf(fv, cst[mt][r], iv * gv);
                cst[mt][r] = cn;
                float hv = ov * tanh_f(cn);
                hF[(mt * 16 + quad * 4 + r) * KPAD + col] = (_Float16)hv;
            }
    };

    // ================= encoder =================
    for (int t = 0; t < TIN; ++t) {
        gemm(KTag<KT_ENC>{}, WpE, bE);
        __syncthreads();              // all A-frag reads done
        pointwise();                  // write h_t
        if ((t & 7) == 0 && (t >> 3) + 1 < 6) loadchunk((t >> 3) + 1);
        if (t + 1 < TIN) xcopy(t + 1);
        __syncthreads();
    }

    // ================= decoder (c resets to 0) =================
    #pragma unroll
    for (int mt = 0; mt < 2; ++mt)
        #pragma unroll
        for (int r = 0; r < 4; ++r) cst[mt][r] = 0.0f;

    for (int t = 0; t < TOUT; ++t) {
        gemm(KTag<KT_DEC>{}, WpD, bD);
        __syncthreads();
        pointwise();
        __syncthreads();
        // dense epilogue -> LDS out buffer (threads 0..255). hF is read-only
        // until the next step's post-gemm barrier -> race-free.
        if (tid < MB * COUT) {
            int m = tid >> 3, o = tid & 7;
            const float* wr = denseW + (t * COUT + o) * HD;
            float s = denseb[t * COUT + o];
            #pragma unroll 4
            for (int j8 = 0; j8 < 32; ++j8) {
                f16x8 hv  = *(const f16x8*)(hF + m * KPAD + j8 * 8);
                float4 w0 = *(const float4*)(wr + j8 * 8);
                float4 w1 = *(const float4*)(wr + j8 * 8 + 4);
                s = fmaf((float)hv[0], w0.x, s);
                s = fmaf((float)hv[1], w0.y, s);
                s = fmaf((float)hv[2], w0.z, s);
                s = fmaf((float)hv[3], w0.w, s);
                s = fmaf((float)hv[4], w1.x, s);
                s = fmaf((float)hv[5], w1.y, s);
                s = fmaf((float)hv[6], w1.z, s);
                s = fmaf((float)hv[7], w1.w, s);
            }
            outS[m * (COUT * TOUT) + o * TOUT + t] = s;
        }
    }

    // ================= coalesced output flush =================
    __syncthreads();
    {
        const float4* src = (const float4*)outS;
        float4* dst = (float4*)(out + (size_t)n0 * (COUT * TOUT));
        for (int i = tid; i < MB * COUT * TOUT / 4; i += 1024)
            dst[i] = src[i];
    }
}

extern "C" void kernel_launch(void* const* d_in, const int* in_sizes, int n_in,
                              void* d_out, int out_size, void* d_ws, size_t ws_size,
                              hipStream_t stream) {
    const float* x       = (const float*)d_in[0];
    const float* enc_Wih = (const float*)d_in[1];
    const float* enc_Whh = (const float*)d_in[2];
    const float* enc_b   = (const float*)d_in[3];
    const float* dec_Whh = (const float*)d_in[4];
    const float* dec_b   = (const float*)d_in[5];
    const float* denseW  = (const float*)d_in[6];
    const float* denseb  = (const float*)d_in[7];
    float* out = (float*)d_out;
    _Float16* wf = (_Float16*)d_ws;   // NREP x 1.09 MB fragment-major fp16 weights

    prep_frags<<<(PREP_TOTAL + 255) / 256, 256, 0, stream>>>(enc_Wih, enc_Whh, dec_Whh, wf);
    seq2seq_mfma<<<8192 / MB, 1024, 0, stream>>>(x, wf, enc_b, dec_b, denseW, denseb, out);
}